// Round 2
// baseline (68.969 us; speedup 1.0000x reference)
//
#include <hip/hip_runtime.h>

#define BB 8
#define CC 3
#define HH 512
#define WW 512

__device__ __forceinline__ float fast_exp2(float x) {
    return __builtin_amdgcn_exp2f(x);
}
__device__ __forceinline__ float fast_log2(float x) {
    return __builtin_amdgcn_logf(x);
}

__global__ __launch_bounds__(256) void smooth_loss_kernel(
    const float* __restrict__ orig, const float* __restrict__ smo,
    float* __restrict__ out)
{
    const int HW = HH * WW;
    const int total = BB * HW;
    const float ws_tab[3] = {1.0f, 0.6065306597126334f, 0.36787944117144233f};
    const float INV_COUNT = 1.0f / 56623104.0f;   // 8*9*3*512*512

    float acc = 0.0f;

    for (int idx = blockIdx.x * blockDim.x + threadIdx.x; idx < total;
         idx += gridDim.x * blockDim.x) {
        const int b  = idx >> 18;          // /(512*512)
        const int hw = idx & (HW - 1);
        const int h  = hw >> 9;
        const int w  = hw & (WW - 1);

        // reflect-101 neighbor indices
        const int hm = (h == 0)      ? 1      : h - 1;
        const int hp = (h == HH - 1) ? HH - 2 : h + 1;
        const int wm = (w == 0)      ? 1      : w - 1;
        const int wp = (w == WW - 1) ? WW - 2 : w + 1;

        const int rows[3] = {hm, h, hp};
        const int cols[3] = {wm, w, wp};

        const float* ob = orig + b * CC * HW;
        const float* sb = smo  + b * CC * HW;

        // center values
        float oc[CC], scv[CC];
        #pragma unroll
        for (int c = 0; c < CC; ++c) {
            oc[c]  = ob[c * HW + h * WW + w];
            scv[c] = sb[c * HW + h * WW + w];
        }

        // edge responses: dx uses (h+1, w) reflected, dy uses (h, w+1) reflected
        float eo = 0.0f, es = 0.0f;
        #pragma unroll
        for (int c = 0; c < CC; ++c) {
            float dxo = oc[c]  - ob[c * HW + hp * WW + w];
            float dyo = oc[c]  - ob[c * HW + h * WW + wp];
            eo += dxo * dxo + dyo * dyo;
            float dxs = scv[c] - sb[c * HW + hp * WW + w];
            float dys = scv[c] - sb[c * HW + h * WW + wp];
            es += dxs * dxs + dys * dys;
        }
        const bool large = (eo < 1.0f) && (es - eo > 1.0f);

        // 9 window offsets
        #pragma unroll
        for (int i = 0; i < 3; ++i) {
            #pragma unroll
            for (int j = 0; j < 3; ++j) {
                const int off = rows[i] * WW + cols[j];
                float ssum = 0.0f;
                float t0, t1, t2;
                {
                    float dfo, dfs;
                    dfo = oc[0]  - ob[0 * HW + off]; ssum += dfo * dfo;
                    dfs = scv[0] - sb[0 * HW + off]; t0 = fabsf(dfs) + 1e-8f;
                    dfo = oc[1]  - ob[1 * HW + off]; ssum += dfo * dfo;
                    dfs = scv[1] - sb[1 * HW + off]; t1 = fabsf(dfs) + 1e-8f;
                    dfo = oc[2]  - ob[2 * HW + off]; ssum += dfo * dfo;
                    dfs = scv[2] - sb[2 * HW + off]; t2 = fabsf(dfs) + 1e-8f;
                }
                if (large) {
                    const float wsv = ws_tab[(i != 1) + (j != 1)];
                    acc += wsv * (t0 * t0 + t1 * t1 + t2 * t2);
                } else {
                    // wr = exp(-0.5 * ssum) = exp2(-0.7213475 * ssum)
                    const float wr = fast_exp2(-0.72134752044448170f * ssum);
                    acc += wr * (fast_exp2(0.8f * fast_log2(t0)) +
                                 fast_exp2(0.8f * fast_log2(t1)) +
                                 fast_exp2(0.8f * fast_log2(t2)));
                }
            }
        }
    }

    acc *= INV_COUNT;

    // wave-64 reduce
    #pragma unroll
    for (int o = 32; o > 0; o >>= 1)
        acc += __shfl_down(acc, o, 64);

    __shared__ float wsum[4];
    const int lane = threadIdx.x & 63;
    const int wid  = threadIdx.x >> 6;
    if (lane == 0) wsum[wid] = acc;
    __syncthreads();
    if (threadIdx.x == 0) {
        float s = wsum[0] + wsum[1] + wsum[2] + wsum[3];
        atomicAdd(out, s);
    }
}

extern "C" void kernel_launch(void* const* d_in, const int* in_sizes, int n_in,
                              void* d_out, int out_size, void* d_ws, size_t ws_size,
                              hipStream_t stream) {
    const float* orig = (const float*)d_in[0];
    const float* smo  = (const float*)d_in[1];
    float* out = (float*)d_out;

    (void)hipMemsetAsync(out, 0, sizeof(float), stream);
    smooth_loss_kernel<<<2048, 256, 0, stream>>>(orig, smo, out);
}

// Round 3
// 56.400 us; speedup vs baseline: 1.2229x; 1.2229x over previous
//
#include <hip/hip_runtime.h>

#define HH 512
#define WW 512
#define TW 32
#define TH 32
#define HS 34              // tile + halo
#define PLANE (HS * HS)    // 1156

__device__ __forceinline__ float fexp2(float x) { return __builtin_amdgcn_exp2f(x); }
__device__ __forceinline__ float flog2(float x) { return __builtin_amdgcn_logf(x); }

__global__ __launch_bounds__(256) void smooth_loss_kernel(
    const float* __restrict__ orig, const float* __restrict__ smo,
    float* __restrict__ out)
{
    __shared__ float L[6 * PLANE];   // planes: o0,o1,o2,s0,s1,s2

    const int tile = blockIdx.x;           // 8 images * 16 * 16 tiles
    const int b    = tile >> 8;
    const int trow = (tile >> 4) & 15;
    const int tcol = tile & 15;
    const int h0 = trow * TH;
    const int w0 = tcol * TW;

    // ---- stage 34x34 halo for 6 planes, reflect-101 at image borders ----
    for (int e = threadIdx.x; e < 6 * PLANE; e += 256) {
        const int p   = e / PLANE;
        const int rem = e - p * PLANE;
        const int tr  = rem / HS;
        const int tc  = rem - tr * HS;
        int gh = h0 - 1 + tr;
        gh = (gh < 0) ? -gh : ((gh > HH - 1) ? (2 * HH - 2 - gh) : gh);
        int gw = w0 - 1 + tc;
        gw = (gw < 0) ? -gw : ((gw > WW - 1) ? (2 * WW - 2 - gw) : gw);
        const float* src = (p < 3) ? orig : smo;
        const int c = (p < 3) ? p : p - 3;
        L[e] = src[(((b * 3 + c) << 18)) + (gh << 9) + gw];
    }
    __syncthreads();

    const float ws_tab[3] = {1.0f, 0.6065306597126334f, 0.36787944117144233f};
    float acc = 0.0f;

    const int tx  = threadIdx.x & 31;
    const int tyb = (threadIdx.x >> 5) << 2;   // 4 consecutive rows per thread

    #pragma unroll
    for (int k = 0; k < 4; ++k) {
        const int ty   = tyb + k;
        const int base = ty * HS + tx;         // window top-left in LDS

        const float oc0 = L[0 * PLANE + base + HS + 1];
        const float oc1 = L[1 * PLANE + base + HS + 1];
        const float oc2 = L[2 * PLANE + base + HS + 1];
        const float sc0 = L[3 * PLANE + base + HS + 1];
        const float sc1 = L[4 * PLANE + base + HS + 1];
        const float sc2 = L[5 * PLANE + base + HS + 1];

        // edge responses (down + right neighbors)
        float eo = 0.0f, es = 0.0f;
        {
            float d;
            d = oc0 - L[0 * PLANE + base + 2 * HS + 1]; eo += d * d;
            d = oc0 - L[0 * PLANE + base + HS + 2];     eo += d * d;
            d = oc1 - L[1 * PLANE + base + 2 * HS + 1]; eo += d * d;
            d = oc1 - L[1 * PLANE + base + HS + 2];     eo += d * d;
            d = oc2 - L[2 * PLANE + base + 2 * HS + 1]; eo += d * d;
            d = oc2 - L[2 * PLANE + base + HS + 2];     eo += d * d;
            d = sc0 - L[3 * PLANE + base + 2 * HS + 1]; es += d * d;
            d = sc0 - L[3 * PLANE + base + HS + 2];     es += d * d;
            d = sc1 - L[4 * PLANE + base + 2 * HS + 1]; es += d * d;
            d = sc1 - L[4 * PLANE + base + HS + 2];     es += d * d;
            d = sc2 - L[5 * PLANE + base + 2 * HS + 1]; es += d * d;
            d = sc2 - L[5 * PLANE + base + HS + 2];     es += d * d;
        }
        const bool large = (eo < 1.0f) && (es - eo > 1.0f);

        // center offset contributes a constant: small: 3*(1e-8)^0.8, large: 3e-16
        acc += large ? 3e-16f : 1.1943215e-6f;

        #pragma unroll
        for (int dy = 0; dy < 3; ++dy) {
            #pragma unroll
            for (int dx = 0; dx < 3; ++dx) {
                if (dy == 1 && dx == 1) continue;
                const int o = base + dy * HS + dx;
                float ssum = 0.0f, d;
                d = oc0 - L[0 * PLANE + o]; ssum += d * d;
                d = oc1 - L[1 * PLANE + o]; ssum += d * d;
                d = oc2 - L[2 * PLANE + o]; ssum += d * d;
                const float t0 = fabsf(sc0 - L[3 * PLANE + o]) + 1e-8f;
                const float t1 = fabsf(sc1 - L[4 * PLANE + o]) + 1e-8f;
                const float t2 = fabsf(sc2 - L[5 * PLANE + o]) + 1e-8f;
                if (large) {
                    const float wsv = ws_tab[(dy != 1) + (dx != 1)];
                    acc += wsv * (t0 * t0 + t1 * t1 + t2 * t2);
                } else {
                    const float wr = fexp2(-0.72134752044448170f * ssum);
                    acc += wr * (fexp2(0.8f * flog2(t0)) +
                                 fexp2(0.8f * flog2(t1)) +
                                 fexp2(0.8f * flog2(t2)));
                }
            }
        }
    }

    acc *= (1.0f / 56623104.0f);   // mean over 8*9*3*512*512

    #pragma unroll
    for (int o = 32; o > 0; o >>= 1)
        acc += __shfl_down(acc, o, 64);

    __shared__ float wsum[4];
    const int lane = threadIdx.x & 63;
    const int wid  = threadIdx.x >> 6;
    if (lane == 0) wsum[wid] = acc;
    __syncthreads();
    if (threadIdx.x == 0) {
        atomicAdd(out, wsum[0] + wsum[1] + wsum[2] + wsum[3]);
    }
}

extern "C" void kernel_launch(void* const* d_in, const int* in_sizes, int n_in,
                              void* d_out, int out_size, void* d_ws, size_t ws_size,
                              hipStream_t stream) {
    const float* orig = (const float*)d_in[0];
    const float* smo  = (const float*)d_in[1];
    float* out = (float*)d_out;

    (void)hipMemsetAsync(out, 0, sizeof(float), stream);
    smooth_loss_kernel<<<2048, 256, 0, stream>>>(orig, smo, out);
}